// Round 1
// baseline (549.229 us; speedup 1.0000x reference)
//
#include <hip/hip_runtime.h>

// PowerSpectrum: values[S,N,L,M,Q] -> out[S,N,L*Q*Q]
// out[s,n,l,q,p] = (1/sqrt(2l+1)) * sum_{m<2l+1} v[s,n,l,m,q] * v[s,n,l,m,p]
// S=4, N=2000, L=4, M=7, Q=64.  Write-BW bound: 524 MB out vs 57 MB in,
// write roofline ~92 us @ 6.3 TB/s (fill kernel demonstrates 6.35 TB/s in-situ).
//
// v2 changes vs v1 (539.9 us):
//  - template<MEFF> compile-time m-trip-count (l is block-uniform, 4 values)
//    -> full unroll, batched LDS reads, ILP instead of serialized
//       ds_read -> lgkmcnt(0) -> fma chains per iteration.
//  - loop interchange: the float4 column read v[m][p] was r-invariant but
//    re-read 4x inside the r-loop; now read once per m (28 -> 7 ds_read_b128
//    per thread at l=3).  LDS pipe cost ~59 us -> ~29 us per CU.
//  - stage only the meff live rows (l=0: 256 B instead of 1792 B).
//  - nontemporal stores for the 524 MB streaming output (zero reuse).

#define PS_S 4
#define PS_N 2000
#define PS_L 4
#define PS_M 7
#define PS_Q 64

typedef float f32x4 __attribute__((ext_vector_type(4)));

template<int MEFF>
__device__ __forceinline__ void ps_compute(const float* __restrict__ vsh,
                                           float* __restrict__ o,
                                           const int t) {
    const float cg = rsqrtf((float)MEFF);
    const int p  = (t & 15) * 4;   // column base (float4)
    const int q0 = t >> 4;         // row within each 16-row band, 0..15

    f32x4 acc[4] = {};             // 4 row-bands x 4 columns per thread

    #pragma unroll
    for (int m = 0; m < MEFF; ++m) {
        // column fragment: read ONCE per m, shared across all 4 row-bands
        const f32x4 b = *(const f32x4*)&vsh[m * PS_Q + p];
        #pragma unroll
        for (int r = 0; r < 4; ++r) {
            // 16-lane broadcast read, conflict-free
            const float a = vsh[m * PS_Q + r * 16 + q0];
            acc[r] += a * b;
        }
    }

    #pragma unroll
    for (int r = 0; r < 4; ++r) {
        f32x4 w = acc[r] * cg;
        // flat offset (r*16+q0)*Q + p: consecutive lanes -> consecutive
        // float4s, each wave stores 1 KB contiguous. Streaming output,
        // no reuse -> nontemporal.
        __builtin_nontemporal_store(w, (f32x4*)&o[(r * 16 + q0) * PS_Q + p]);
    }
}

__global__ __launch_bounds__(256) void PowerSpectrum_kernel(
    const float* __restrict__ values, float* __restrict__ out) {
    // one block per (s, n, l); bid = ((s*N + n)*L + l)
    const int bid = blockIdx.x;
    const int l = bid & (PS_L - 1);          // L == 4 (power of 2)
    const float* __restrict__ vin = values + (size_t)bid * (PS_M * PS_Q);
    float* __restrict__ o = out + (size_t)bid * (PS_Q * PS_Q);

    __shared__ float v[PS_M * PS_Q];         // 1792 B

    const int t = threadIdx.x;
    const int meff = 2 * l + 1;              // block-uniform

    // stage only the live rows: meff*64 floats = meff*16 float4, coalesced
    if (t < meff * (PS_Q / 4)) {
        ((f32x4*)v)[t] = ((const f32x4*)vin)[t];
    }
    __syncthreads();

    switch (l) {                             // block-uniform dispatch
        case 0:  ps_compute<1>(v, o, t); break;
        case 1:  ps_compute<3>(v, o, t); break;
        case 2:  ps_compute<5>(v, o, t); break;
        default: ps_compute<7>(v, o, t); break;
    }
}

extern "C" void kernel_launch(void* const* d_in, const int* in_sizes, int n_in,
                              void* d_out, int out_size, void* d_ws, size_t ws_size,
                              hipStream_t stream) {
    const float* values = (const float*)d_in[0];
    float* out = (float*)d_out;
    const int n_blocks = PS_S * PS_N * PS_L;   // 32000
    PowerSpectrum_kernel<<<n_blocks, 256, 0, stream>>>(values, out);
}